// Round 3
// baseline (145.167 us; speedup 1.0000x reference)
//
#include <hip/hip_runtime.h>
#include <math.h>

#define N 8192
#define D 128
#define MARGIN 0.2f
#define PD_EPS 1e-6f
#define NCHUNK 16
#define CHUNKJ (N / NCHUNK)   // 512 j per chunk

typedef __attribute__((ext_vector_type(8))) short bf16x8;  // 8 bf16 = 4 VGPRs
typedef __attribute__((ext_vector_type(4))) float f32x4;

__device__ __forceinline__ unsigned short f2bf(float f) {
    unsigned u = __float_as_uint(f);
    u += 0x7FFFu + ((u >> 16) & 1u);   // round-to-nearest-even
    return (unsigned short)(u >> 16);
}
__device__ __forceinline__ unsigned umn(unsigned a, unsigned b) { return a < b ? a : b; }
__device__ __forceinline__ unsigned umx(unsigned a, unsigned b) { return a > b ? a : b; }

// ---------------- kernel 1: normalize -> bf16 rows + inv-norm + packed meta ---
__global__ __launch_bounds__(256) void k_normalize(const float* __restrict__ z,
                                                   const int* __restrict__ labels,
                                                   const int* __restrict__ subjects,
                                                   unsigned short* __restrict__ znb,
                                                   float* __restrict__ invn,
                                                   int* __restrict__ meta) {
    int row  = blockIdx.x * 4 + (threadIdx.x >> 6);
    int lane = threadIdx.x & 63;
    float2 v = ((const float2*)(z + (size_t)row * D))[lane];
    float ss = v.x * v.x + v.y * v.y;
    #pragma unroll
    for (int m = 1; m < 64; m <<= 1) ss += __shfl_xor(ss, m, 64);
    float norm = fmaxf(sqrtf(ss), 1e-12f);
    float ox = v.x / norm, oy = v.y / norm;
    ushort2 b; b.x = f2bf(ox); b.y = f2bf(oy);
    ((ushort2*)(znb + (size_t)row * D))[lane] = b;
    if (lane == 0) {
        invn[row] = 1.0f / norm;
        meta[row] = labels[row] * 32 + subjects[row];   // 9 bits: label(4)|subject(5)
    }
}

// ---------------- kernel 2: MFMA mining --------------------------------------
// ROUND-3 RESTRUCTURE: wave owns 32 anchors (2 utiles), not 64. Rationale:
// occupancy was register-limited, not grid-limited — VGPR_Count (116) EXCLUDES
// the 64 AGPRs of acc[4][4]; 180 total regs -> 2 waves/SIMD, which no grid size
// fixes. Halving the anchor tile gives afrag 32 + acc 32(AGPR) + bp/bn 16 +
// mi 8 + temps ~ 124 total <= 128, so __launch_bounds__(256,4) is satisfiable
// (round-1's spill disaster was demanding 180->64; here we demand ~124->128).
// Grid 64x16 = 1024 blocks = exactly 4 blocks/CU, single full-residency pass.
__global__ __launch_bounds__(256, 4) void k_mine(const unsigned short* __restrict__ znb,
                                                 const int* __restrict__ meta,
                                                 unsigned* __restrict__ posk,
                                                 unsigned* __restrict__ negk) {
    const int wave = threadIdx.x >> 6;
    const int lane = threadIdx.x & 63;
    const int m    = lane & 15;     // A/B operand row within 16-tile
    const int quad = lane >> 4;     // k-slice selector / C-row group
    const int iw   = (blockIdx.x * 4 + wave) * 32;
    const int jc   = blockIdx.y;
    const int jbase = jc * CHUNKJ;

    // persistent A fragments: [utile][kstep], lane holds row iw+u*16+m,
    // k = s*32 + quad*8 .. +8  (A[m=lane&15][k=quad*8+j] layout, m89-verified)
    bf16x8 afrag[2][4];
    #pragma unroll
    for (int u = 0; u < 2; ++u)
        #pragma unroll
        for (int s = 0; s < 4; ++s)
            afrag[u][s] = *(const bf16x8*)(znb + (size_t)(iw + u * 16 + m) * D + s * 32 + quad * 8);

    // meta for this lane's 8 C-row slots: i = iw + u*16 + quad*4 + r
    int mi[8];
    #pragma unroll
    for (int u = 0; u < 2; ++u)
        #pragma unroll
        for (int r = 0; r < 4; ++r)
            mi[u * 4 + r] = meta[iw + u * 16 + quad * 4 + r];

    unsigned bp[8], bn[8];
    #pragma unroll
    for (int s = 0; s < 8; ++s) { bp[s] = 0xFFFFFFFFu; bn[s] = 0u; }

    #pragma unroll 1   // keep the loop body compact under the 128-reg budget
    for (int t = 0; t < CHUNKJ / 64; ++t) {
        const int jt = jbase + t * 64;

        // hoist the j-metadata loads so they overlap the MFMA block
        int mjv[4];
        #pragma unroll
        for (int v = 0; v < 4; ++v) mjv[v] = meta[jt + v * 16 + m];

        f32x4 acc[2][4];
        #pragma unroll
        for (int u = 0; u < 2; ++u)
            #pragma unroll
            for (int v = 0; v < 4; ++v)
                acc[u][v] = (f32x4){0.f, 0.f, 0.f, 0.f};

        #pragma unroll
        for (int s = 0; s < 4; ++s) {
            bf16x8 bf[4];
            #pragma unroll
            for (int v = 0; v < 4; ++v)
                bf[v] = *(const bf16x8*)(znb + (size_t)(jt + v * 16 + m) * D + s * 32 + quad * 8);
            #pragma unroll
            for (int u = 0; u < 2; ++u)
                #pragma unroll
                for (int v = 0; v < 4; ++v)
                    acc[u][v] = __builtin_amdgcn_mfma_f32_16x16x32_bf16(afrag[u][s], bf[v], acc[u][v], 0, 0, 0);
        }

        // epilogue: C/D layout col=lane&15, row=quad*4+reg (m89/m91-verified)
        #pragma unroll
        for (int v = 0; v < 4; ++v) {
            const int jv = jt + v * 16 + m;     // this lane's j for tile v
            #pragma unroll
            for (int u = 0; u < 2; ++u)
                #pragma unroll
                for (int r = 0; r < 4; ++r) {
                    float dot = acc[u][v][r];
                    unsigned key = (__float_as_uint(dot + 2.0f) & 0xFFFFE000u) | (unsigned)jv;
                    unsigned x = (unsigned)(mi[u * 4 + r] ^ mjv[v]);
                    bool pos = (x - 1u) < 31u;                 // x!=0 && x<32, one cmp
                    bool neg = (x != 0u) && ((x & 31u) == 0u); // diff class, same subject
                    bp[u * 4 + r] = umn(bp[u * 4 + r], pos ? key : 0xFFFFFFFFu);
                    bn[u * 4 + r] = umx(bn[u * 4 + r], neg ? key : 0u);
                }
        }
    }

    // merge across the 16 lanes (different j) sharing each (quad, slot)
    #pragma unroll
    for (int mm = 1; mm < 16; mm <<= 1)
        #pragma unroll
        for (int s = 0; s < 8; ++s) {
            bp[s] = umn(bp[s], (unsigned)__shfl_xor((int)bp[s], mm, 64));
            bn[s] = umx(bn[s], (unsigned)__shfl_xor((int)bn[s], mm, 64));
        }
    if (m == 0) {
        #pragma unroll
        for (int u = 0; u < 2; ++u)
            #pragma unroll
            for (int r = 0; r < 4; ++r) {
                int i = iw + u * 16 + quad * 4 + r;
                posk[(size_t)jc * N + i] = bp[u * 4 + r];
                negk[(size_t)jc * N + i] = bn[u * 4 + r];
            }
    }
}

// ---------------- kernel 3: combine chunks + fp32 hinge ----------------------
__global__ __launch_bounds__(256) void k_final(const float* __restrict__ z,
                                               const float* __restrict__ invn,
                                               const unsigned* __restrict__ posk,
                                               const unsigned* __restrict__ negk,
                                               float* __restrict__ per, float* __restrict__ vld) {
    int row  = blockIdx.x * 4 + (threadIdx.x >> 6);
    int lane = threadIdx.x & 63;

    // lane-parallel chunk combine: lanes 0-15 min posk, lanes 32-47 max negk
    // (1 vector load + 4 shuffles instead of 16 serial broadcast loads each)
    {
        unsigned c = (unsigned)(lane & 15);
        bool isPos = lane < 32;
        unsigned key = isPos ? posk[(size_t)c * N + row] : negk[(size_t)c * N + row];
        #pragma unroll
        for (int mm = 1; mm < 16; mm <<= 1) {
            unsigned o = (unsigned)__shfl_xor((int)key, mm, 64);
            key = isPos ? umn(key, o) : umx(key, o);
        }
        unsigned mp = (unsigned)__shfl((int)key, 0, 64);
        unsigned mn = (unsigned)__shfl((int)key, 32, 64);

        bool valid = (mp != 0xFFFFFFFFu) && (mn != 0u);
        int pi = valid ? (int)(mp & 8191u) : 0;
        int ni = valid ? (int)(mn & 8191u) : 0;
        float ia = invn[row], ip = invn[pi], iq = invn[ni];
        float2 a = ((const float2*)(z + (size_t)row * D))[lane];
        float2 p = ((const float2*)(z + (size_t)pi  * D))[lane];
        float2 q = ((const float2*)(z + (size_t)ni  * D))[lane];
        float dx = a.x * ia - p.x * ip + PD_EPS, dy = a.y * ia - p.y * ip + PD_EPS;
        float sap = dx * dx + dy * dy;
        dx = a.x * ia - q.x * iq + PD_EPS; dy = a.y * ia - q.y * iq + PD_EPS;
        float san = dx * dx + dy * dy;
        #pragma unroll
        for (int m = 1; m < 64; m <<= 1) {
            sap += __shfl_xor(sap, m, 64);
            san += __shfl_xor(san, m, 64);
        }
        if (lane == 0) {
            float l = fmaxf(sqrtf(sap) - sqrtf(san) + MARGIN, 0.0f);
            per[row] = valid ? l : 0.0f;
            vld[row] = valid ? 1.0f : 0.0f;
        }
    }
}

// ---------------- kernel 4: deterministic final reduce -----------------------
__global__ __launch_bounds__(256) void k_reduce(const float* __restrict__ per,
                                                const float* __restrict__ vld,
                                                float* __restrict__ out) {
    __shared__ float s1[256], s2[256];
    int t = threadIdx.x;
    float a = 0.f, b = 0.f;
    for (int i = t; i < N; i += 256) { a += per[i]; b += vld[i]; }
    s1[t] = a; s2[t] = b;
    __syncthreads();
    for (int w = 128; w > 0; w >>= 1) {
        if (t < w) { s1[t] += s1[t + w]; s2[t] += s2[t + w]; }
        __syncthreads();
    }
    if (t == 0) {
        float cnt = s2[0];
        out[0] = (cnt > 0.f) ? s1[0] / fmaxf(cnt, 1.f) : 0.f;
    }
}

extern "C" void kernel_launch(void* const* d_in, const int* in_sizes, int n_in,
                              void* d_out, int out_size, void* d_ws, size_t ws_size,
                              hipStream_t stream) {
    const float* z        = (const float*)d_in[0];
    const int*   labels   = (const int*)d_in[1];
    const int*   subjects = (const int*)d_in[2];
    float* out = (float*)d_out;

    char* ws = (char*)d_ws;
    unsigned short* znb = (unsigned short*)(ws);            // 2 MB
    float*    invn = (float*)   (ws + 2097152);             // 32 KB
    int*      meta = (int*)     (ws + 2129920);             // 32 KB
    unsigned* posk = (unsigned*)(ws + 2162688);             // 512 KB (16 chunks)
    unsigned* negk = (unsigned*)(ws + 2686976);             // 512 KB
    float*    per  = (float*)   (ws + 3211264);             // 32 KB
    float*    vld  = (float*)   (ws + 3244032);             // 32 KB

    k_normalize<<<dim3(N / 4), dim3(256), 0, stream>>>(z, labels, subjects, znb, invn, meta);
    k_mine<<<dim3(64, NCHUNK), dim3(256), 0, stream>>>(znb, meta, posk, negk);
    k_final<<<dim3(N / 4), dim3(256), 0, stream>>>(z, invn, posk, negk, per, vld);
    k_reduce<<<dim3(1), dim3(256), 0, stream>>>(per, vld, out);
}